// Round 5
// baseline (241.386 us; speedup 1.0000x reference)
//
#include <hip/hip_runtime.h>

// Problem constants (from reference setup_inputs): B=2, H=W=128.
#define B_ITEMS 2
#define W_IMG   128
#define N_PTS   16384          // H*W
#define QS      2              // col-split across blocks
#define CH_GRID 2048           // max Utot = 4 s * 256 rowgroups * QS
#define BIGF    3.4e38f

// ---------------------------------------------------------------------------
// Kernel 1: compaction (R7 structure, proven). Also inits the rmG min table
// (65536 slots == 256 blocks x 256 threads) and zeroes out[0].
//   raw[pos] = (x, y, z, |q|^2)        row side
//   tf [pos] = (-2x, -2y, -2z, |q|^2)  col side: d = |p|^2 + fma3(p, tf)
// ---------------------------------------------------------------------------
__global__ __launch_bounds__(256) void prep_kernel(
        const float* __restrict__ pred,
        const float* __restrict__ gt,
        const int*   __restrict__ mask,
        const float* fxp, const float* fyp,
        const float* cxp, const float* cyp,
        int*    __restrict__ cnt,       // [0]=np0 [1]=np1 [2]=ng0 [3]=ng1
        float4* __restrict__ pR, float4* __restrict__ gR,   // raw   [B][N]
        float4* __restrict__ pT, float4* __restrict__ gT,   // transf[B][N]
        float*  __restrict__ rmG,       // [4][N_PTS] per-row min table
        float*  __restrict__ out) {
    int s    = blockIdx.x >> 6;
    int b    = s & 1;
    int isG  = s >> 1;
    int tid  = threadIdx.x;
    int idx  = (blockIdx.x & 63) * 256 + tid;
    int lane = tid & 63, w = tid >> 6;

    if (blockIdx.x == 0 && tid == 0) out[0] = 0.0f;
    rmG[(blockIdx.x << 8) + tid] = BIGF;

    float x, y, z;
    if (!isG) {
        float fx = *fxp, fy = *fyp, cx = *cxp, cy = *cyp;
        float u = (float)(idx & (W_IMG - 1));
        float v = (float)(idx >> 7);
        z = pred[b * N_PTS + idx];
        x = (u - cx) / fx * z;
        y = (v - cy) / fy * z;
    } else {
        x = gt[(b * 3 + 0) * N_PTS + idx];
        y = gt[(b * 3 + 1) * N_PTS + idx];
        z = gt[(b * 3 + 2) * N_PTS + idx];
    }
    int  mv = mask[b * N_PTS + idx];
    bool ok = (mv > 0) && (((x + y) + z) != 0.0f);

    unsigned long long bal = __ballot(ok);
    int nw  = __popcll(bal);
    int pre = __popcll(bal & ((1ull << lane) - 1ull));

    __shared__ int wbase[4];
    __shared__ int blockbase;
    if (lane == 0) wbase[w] = nw;
    __syncthreads();
    if (tid == 0) {
        int s0 = 0;
#pragma unroll
        for (int i = 0; i < 4; ++i) { int t = wbase[i]; wbase[i] = s0; s0 += t; }
        blockbase = s0 ? atomicAdd(&cnt[s], s0) : 0;
    }
    __syncthreads();

    if (ok) {
        int pos = blockbase + wbase[w] + pre;
        float ps = fmaf(z, z, fmaf(y, y, x * x));
        float4* __restrict__ raw = (isG ? gR : pR) + b * N_PTS;
        float4* __restrict__ tf  = (isG ? gT : pT) + b * N_PTS;
        raw[pos] = make_float4(x, y, z, ps);
        tf[pos]  = make_float4(-2.0f * x, -2.0f * y, -2.0f * z, ps);
    }
}

// ---------------------------------------------------------------------------
// Kernel 2 (R15): register-pinned, DIRECT-GLOBAL chamfer. No LDS in the hot
// loop at all.
// R4 lesson (PMC: VGPR=52 < the 64-reg live set, VALUBusy 15%): the compiler
// SANK the A-row loads into the tile loop (re-loading 16 float4/tile from
// L1) -> latency-bound. Fix 1: asm-pin the row tile after loading (sinking
// becomes illegal). Fix 2: B is <=512 KB total = L2-resident (R4 FETCH
// 1.65 MB confirms), so read cols straight from global: with tc=lane&15 a
// wave reads 16 consecutive float4 = one 256B segment (4 lanes/address,
// coalesced broadcast). Per 2 cols: 2 global_load_dwordx4 + 112 VALU inst
// -> 1:56 VMEM:VALU, L2 latency hidden under compute. Zero barriers, zero
// staging, zero LDS-size hazards. (R2 lesson: scalar-cache streaming
// serializes — these are VECTOR loads, different path, MLP-capable.)
//  - block = 64 rows x col-half (QS=2); 2048 blocks, 4 waves/SIMD at ~90
//    VGPR (<=128 cap from __launch_bounds__(256,4)).
//  - 16 rows/thread (tc=lane&15, tr=lane>>4), 2 cols/iter, fmin3 pairing:
//    3.5 VALU ops/pair -> ~12 us floor.
//  - combine: 4 shfl_xor (tc fold) -> sm[w][row] -> ONE barrier -> 4-way
//    min -> atomicMin into rmG (int-order on nonneg floats; proven R1-R4).
//  - finish fused via done-counter (proven R2/R4): last block sums rmG.
// ---------------------------------------------------------------------------
__global__ __launch_bounds__(256, 4) void chamfer_kernel(
        const int*    __restrict__ cnt,
        const float4* __restrict__ pR, const float4* __restrict__ gR,
        const float4* __restrict__ pT, const float4* __restrict__ gT,
        float* __restrict__ rmG,
        int*   __restrict__ done,
        float* __restrict__ out) {
    int np0 = cnt[0], np1 = cnt[1], ng0 = cnt[2], ng1 = cnt[3];
    int naArr[4] = {np0, ng0, np1, ng1};
    int nbArr[4] = {ng0, np0, ng1, np1};
    const float4* Arow[4] = {pR, gR, pR + N_PTS, gR + N_PTS};
    const float4* Bcol[4] = {gT, pT, gT + N_PTS, pT + N_PTS};

    int units[4];
    int Utot = 0;
#pragma unroll
    for (int i = 0; i < 4; ++i) {
        units[i] = (naArr[i] > 0 && nbArr[i] > 0) ? (((naArr[i] + 63) >> 6) * QS) : 0;
        Utot += units[i];
    }

    int tid  = threadIdx.x;
    int lane = tid & 63;
    int w    = __builtin_amdgcn_readfirstlane(tid >> 6);   // wave id, SGPR

    __shared__ float sm[4][64];
    __shared__ float wsum[4];
    __shared__ int   lastFlag;

    int u = blockIdx.x;
    if (u < Utot) {
        int s = 0;
        while (u >= units[s]) { u -= units[s]; ++s; }
        int na = naArr[s], nb = nbArr[s];
        const float4* __restrict__ A  = Arow[s];
        const float4* __restrict__ Bp = Bcol[s];
        int q       = u & (QS - 1);
        int rowbase = (u >> 1) * 64;

        int Lq  = (nb + QS - 1) / QS;        // per-block col range
        int cb0 = q * Lq;
        int cc  = min(nb - cb0, Lq); if (cc < 0) cc = 0;
        int Lw  = (cc + 3) >> 2;             // per-wave col range
        int wb  = cb0 + w * Lw;
        int wc  = min(cc - w * Lw, Lw); if (wc < 0) wc = 0;

        int tc = lane & 15, tr = lane >> 4;

        // 16 rows/thread: row = rowbase + a*4 + tr (<= 16383 always; rows
        // >= na read finite ws poison, gated at the atomicMin). asm-pin
        // forces the 48 xyz values into VGPRs NOW -> sinking illegal.
        float px[16], py[16], pz[16], rm[16];
#pragma unroll
        for (int a = 0; a < 16; ++a) {
            float4 v = A[rowbase + a * 4 + tr];
            px[a] = v.x; py[a] = v.y; pz[a] = v.z;
            rm[a] = BIGF;
            asm volatile("" : "+v"(px[a]), "+v"(py[a]), "+v"(pz[a]));
        }

        // thread handles cols {wb + 32k + tc, wb + 32k + 16 + tc}
        int nIt = (wc + 31) >> 5;            // uniform per wave; can be 0

#define LOADC(J, DST) { \
        int j_ = (J); \
        float4 v_ = Bp[min(wb + j_, N_PTS - 1)]; \
        bool ok_ = j_ < wc; \
        DST.x = ok_ ? v_.x : 0.0f; DST.y = ok_ ? v_.y : 0.0f; \
        DST.z = ok_ ? v_.z : 0.0f; DST.w = ok_ ? v_.w : BIGF; }

#pragma unroll 2
        for (int it = 0; it < nIt; ++it) {
            float4 c0, c1;
            int j0 = it * 32 + tc;
            if ((it + 1) * 32 <= wc) {       // full group: uniform fast path
                c0 = Bp[wb + j0];
                c1 = Bp[wb + j0 + 16];
            } else {                         // ragged tail: sentinel cols
                LOADC(j0, c0)
                LOADC(j0 + 16, c1)
            }
#pragma unroll
            for (int a = 0; a < 16; ++a) {
                float d0 = fmaf(px[a], c0.x,
                             fmaf(py[a], c0.y, fmaf(pz[a], c0.z, c0.w)));
                float d1 = fmaf(px[a], c1.x,
                             fmaf(py[a], c1.y, fmaf(pz[a], c1.z, c1.w)));
                rm[a] = fminf(fminf(rm[a], d0), d1);      // v_min3_f32
            }
        }
#undef LOADC

        // fold over tc (lane bits 0..3): lanes sharing (tr,a) share a row
#pragma unroll
        for (int a = 0; a < 16; ++a) {
            float v = rm[a];
            v = fminf(v, __shfl_xor(v, 1, 64));
            v = fminf(v, __shfl_xor(v, 2, 64));
            v = fminf(v, __shfl_xor(v, 4, 64));
            v = fminf(v, __shfl_xor(v, 8, 64));
            rm[a] = v;
        }
        if (tc == 0) {
#pragma unroll
            for (int a = 0; a < 16; ++a) sm[w][a * 4 + tr] = rm[a];
        }
        __syncthreads();                     // the ONE barrier (wave combine)
        if (tid < 64) {
            float m = fminf(fminf(sm[0][tid], sm[1][tid]),
                            fminf(sm[2][tid], sm[3][tid]));
            int r2 = rowbase + tid;
            if (r2 < na) {
                float psv = A[r2].w;         // |p|^2 (L1-hot reload)
                float vr  = fmaxf(m + psv, 0.0f);    // nonneg -> int order ok
                atomicMin((int*)&rmG[(s << 14) + r2], __float_as_int(vr));
            }
        }
    }

    // -------- done-counter: last block (of all CH_GRID) does the final sum.
    __syncthreads();                         // block-uniform path
    __threadfence();
    if (tid == 0) {
        int old = atomicAdd(done, 1);
        lastFlag = (old == (int)gridDim.x - 1) ? 1 : 0;
    }
    __syncthreads();

    if (lastFlag) {                          // block-uniform branch
        int* rmGi = (int*)rmG;
        float acc = 0.0f;
#pragma unroll 1
        for (int s2 = 0; s2 < 4; ++s2) {
            if (nbArr[s2] <= 0) continue;    // no partner side -> contributes 0
            int na2  = naArr[s2];
            int base = s2 << 14;
            for (int k = tid; k < na2; k += 256)   // compacted prefix only
                acc += __int_as_float(__hip_atomic_load(&rmGi[base + k],
                        __ATOMIC_RELAXED, __HIP_MEMORY_SCOPE_AGENT));
        }
#pragma unroll
        for (int off = 32; off > 0; off >>= 1)
            acc += __shfl_down(acc, off, 64);
        if (lane == 0) wsum[tid >> 6] = acc;
        __syncthreads();
        if (tid == 0)
            out[0] = (wsum[0] + wsum[1] + wsum[2] + wsum[3]) * (1.0f / B_ITEMS);
    }
}

extern "C" void kernel_launch(void* const* d_in, const int* in_sizes, int n_in,
                              void* d_out, int out_size, void* d_ws, size_t ws_size,
                              hipStream_t stream) {
    const float* pred = (const float*)d_in[0];
    const float* gt   = (const float*)d_in[1];
    const int*   mask = (const int*)  d_in[2];
    const float* fx   = (const float*)d_in[3];
    const float* fy   = (const float*)d_in[4];
    const float* cx   = (const float*)d_in[5];
    const float* cy   = (const float*)d_in[6];
    float* out = (float*)d_out;

    // ws: [0,256) cnt+done | pR 512K | gR 512K | pT 512K | gT 512K | rmG 256K
    char* ws = (char*)d_ws;
    size_t SEG = (size_t)B_ITEMS * N_PTS * 16;
    int*    cnt  = (int*)ws;
    int*    done = cnt + 4;
    float4* pR   = (float4*)(ws + 256);
    float4* gR   = (float4*)(ws + 256 + SEG);
    float4* pT   = (float4*)(ws + 256 + 2 * SEG);
    float4* gT   = (float4*)(ws + 256 + 3 * SEG);
    float*  rmG  = (float*) (ws + 256 + 4 * SEG);

    hipMemsetAsync(cnt, 0, 32, stream);      // cnt[0..3] + done

    prep_kernel<<<dim3(256), 256, 0, stream>>>(
        pred, gt, mask, fx, fy, cx, cy, cnt, pR, gR, pT, gT, rmG, out);

    chamfer_kernel<<<dim3(CH_GRID), 256, 0, stream>>>(
        cnt, pR, gR, pT, gT, rmG, done, out);
}